// Round 2
// baseline (6216.204 us; speedup 1.0000x reference)
//
#include <hip/hip_runtime.h>
#include <hip/hip_bf16.h>
#include <math.h>

// TransformerBlock3D: B=8, C=128, S=32 (N=32768), HEADS=8 (dim_head=16), MLP=512
// Round 2: crash fix (round 1 used ~672MB d_ws -> OOB fault). New structure:
//  - attention collapsed algebraically: G = X X^T (128x128/batch), gram = Wq G Wk^T,
//    M'_b = I + proj_w . blockdiag(attn_b) . Wv  ->  x1pre = M'_b x + proj_b
//  - d_out (134 MB) is the activation buffer: x1pre -> LN1 in-place -> fused MLP
//    in-place -> LN2 in-place. d_ws usage: ~35 MB. Static LDS <= 64 KB everywhere.

#define N_SP 32768
typedef __hip_bfloat16 bf16;
static const size_t DS = (size_t)128 * N_SP;   // per-batch stride of [8][128][32768]

// ---------- tiny transpose: out[c*R + r] = in[r*C + c] ----------
__global__ __launch_bounds__(256) void k_transpose(const float* __restrict__ in,
                                                   float* __restrict__ out,
                                                   int R, int Ccols) {
    int idx = blockIdx.x * 256 + threadIdx.x;
    if (idx >= R * Ccols) return;
    int r = idx / Ccols, c = idx % Ccols;
    out[c * R + r] = in[idx];
}

// ---------- covariance partials: Gpart[b*64+kb][i][j] = sum_{n in slice} x_i x_j ----------
__global__ __launch_bounds__(256) void k_cov(const float* __restrict__ x,
                                             float* __restrict__ Gpart) {
    __shared__ __align__(16) float xs[64 * 132];   // [n][c], pad 132
    const int kb = blockIdx.x, b = blockIdx.y;
    const int t = threadIdx.x;
    const int i0 = (t >> 4) * 8, j0 = (t & 15) * 8;
    float acc[64];
#pragma unroll
    for (int k = 0; k < 64; ++k) acc[k] = 0.f;
    const float* xb = x + (size_t)b * DS;
    for (int sub = 0; sub < 8; ++sub) {
        const int n0 = kb * 512 + sub * 64;
        __syncthreads();
#pragma unroll
        for (int r = 0; r < 32; ++r) {
            int id = r * 256 + t;
            int c = id >> 6, nn = id & 63;
            xs[nn * 132 + c] = xb[(size_t)c * N_SP + n0 + nn];
        }
        __syncthreads();
#pragma unroll 4
        for (int nn = 0; nn < 64; ++nn) {
            float av[8], bv[8];
            *(float4*)&av[0] = *(const float4*)&xs[nn * 132 + i0];
            *(float4*)&av[4] = *(const float4*)&xs[nn * 132 + i0 + 4];
            *(float4*)&bv[0] = *(const float4*)&xs[nn * 132 + j0];
            *(float4*)&bv[4] = *(const float4*)&xs[nn * 132 + j0 + 4];
#pragma unroll
            for (int ii = 0; ii < 8; ++ii)
#pragma unroll
                for (int jj = 0; jj < 8; ++jj)
                    acc[ii * 8 + jj] = fmaf(av[ii], bv[jj], acc[ii * 8 + jj]);
        }
    }
    float* gp = Gpart + ((size_t)b * 64 + kb) * 16384;
#pragma unroll
    for (int ii = 0; ii < 8; ++ii)
#pragma unroll
        for (int jj = 0; jj < 8; jj += 4) {
            float4 v = make_float4(acc[ii * 8 + jj], acc[ii * 8 + jj + 1],
                                   acc[ii * 8 + jj + 2], acc[ii * 8 + jj + 3]);
            *(float4*)&gp[(i0 + ii) * 128 + j0 + jj] = v;
        }
}

// ---------- reduce partials: G[b][ij] = sum_kb Gpart[b*64+kb][ij] ----------
__global__ __launch_bounds__(256) void k_greduce(const float* __restrict__ Gpart,
                                                 float* __restrict__ G) {
    int tid = blockIdx.x * 256 + threadIdx.x;   // 131072 total
    int b = tid >> 14, ij = tid & 16383;
    float s = 0.f;
    for (int kb = 0; kb < 64; ++kb)
        s += Gpart[((size_t)b * 64 + kb) * 16384 + ij];
    G[tid] = s;
}

// ---------- gram + softmax: attn[b][h][i][j] = softmax_j(0.25 * Wq_hi G Wk_hj^T) ----------
__global__ __launch_bounds__(256) void k_gram_small(const float* __restrict__ G,
                                                    const float* __restrict__ qkv_w,
                                                    float* __restrict__ attn) {
    __shared__ float t1[16 * 132];   // t1[i][c'] = (Wq_h G)[i][c']
    __shared__ float sg[16 * 16];
    const int bh = blockIdx.x;
    const int b = bh >> 3, h = bh & 7;
    const int t = threadIdx.x;
    {
        const int i = t >> 4, c20 = (t & 15) * 8;
        const float* wq = qkv_w + (size_t)(h * 16 + i) * 128;
        const float* Gb = G + (size_t)b * 16384;
        float a[8];
#pragma unroll
        for (int k = 0; k < 8; ++k) a[k] = 0.f;
        for (int c = 0; c < 128; ++c) {
            float w = wq[c];
            const float* grow = Gb + c * 128 + c20;
#pragma unroll
            for (int k = 0; k < 8; ++k) a[k] = fmaf(w, grow[k], a[k]);
        }
#pragma unroll
        for (int k = 0; k < 8; ++k) t1[i * 132 + c20 + k] = a[k];
    }
    __syncthreads();
    {
        const int i = t >> 4, j = t & 15;
        const float* wk = qkv_w + (size_t)(128 + h * 16 + j) * 128;
        float s = 0.f;
        for (int c2 = 0; c2 < 128; ++c2) s = fmaf(t1[i * 132 + c2], wk[c2], s);
        sg[i * 16 + j] = s * 0.25f;   // SCALE = 16^-0.5 ... squared? no: 0.25 = 1/sqrt(16)
    }
    __syncthreads();
    if (t < 16) {
        float mx = -1e30f;
#pragma unroll
        for (int j = 0; j < 16; ++j) mx = fmaxf(mx, sg[t * 16 + j]);
        float e[16], sum = 0.f;
#pragma unroll
        for (int j = 0; j < 16; ++j) { e[j] = expf(sg[t * 16 + j] - mx); sum += e[j]; }
        float inv = 1.0f / sum;
#pragma unroll
        for (int j = 0; j < 16; ++j)
            attn[((size_t)bh * 16 + t) * 16 + j] = e[j] * inv;
    }
}

// ---------- fold: MT[b][c][o] = (I + P . blockdiag(attn) . Wv)[o][c] ----------
__global__ __launch_bounds__(256, 2) void k_mfold(const float* __restrict__ attn,
                                                  const float* __restrict__ qkv_w,
                                                  const float* __restrict__ PT,
                                                  float* __restrict__ MT) {
    __shared__ float t2[128 * 128];   // exactly 64 KB; t2[hi][c] then reused for merge
    const int b = blockIdx.x, t = threadIdx.x;
    {
        const int hi = t >> 1, c0 = (t & 1) * 64;
        const int h = hi >> 4;
        const float* at = attn + ((size_t)b * 128 + hi) * 16;
        float a[16];
#pragma unroll
        for (int j = 0; j < 16; ++j) a[j] = at[j];
        float sc[64];
#pragma unroll
        for (int c = 0; c < 64; ++c) sc[c] = 0.f;
        for (int j = 0; j < 16; ++j) {
            const float* wv = qkv_w + (size_t)(256 + h * 16 + j) * 128 + c0;
            float aj = a[j];
#pragma unroll
            for (int c = 0; c < 64; ++c) sc[c] = fmaf(aj, wv[c], sc[c]);
        }
#pragma unroll
        for (int c = 0; c < 64; ++c) t2[hi * 128 + c0 + c] = sc[c];
    }
    __syncthreads();
    const int c = t & 127, half = t >> 7;
    float acc[128];
#pragma unroll
    for (int o = 0; o < 128; ++o) acc[o] = 0.f;
    for (int ci = half * 64; ci < half * 64 + 64; ++ci) {
        float s = t2[ci * 128 + c];
        const float* pt = PT + ci * 128;
#pragma unroll
        for (int o = 0; o < 128; ++o) acc[o] = fmaf(pt[o], s, acc[o]);
    }
    __syncthreads();
    if (half) {
#pragma unroll
        for (int o = 0; o < 128; ++o) t2[c * 128 + o] = acc[o];
    }
    __syncthreads();
    if (!half) {
        float* m = MT + (size_t)b * 16384 + (size_t)c * 128;
#pragma unroll
        for (int o = 0; o < 128; ++o)
            m[o] = acc[o] + t2[c * 128 + o] + (o == c ? 1.0f : 0.0f);
    }
}

// ---------- x1pre = M'_b x + proj_b (residual folded via +I), LN1 stats ----------
__global__ __launch_bounds__(256, 2) void k_attnproj(const float* __restrict__ x,
                                                     const float* __restrict__ MT,
                                                     const float* __restrict__ proj_b,
                                                     float* __restrict__ xout,
                                                     float* __restrict__ st) {
    const int b = blockIdx.y;
    const int n = blockIdx.x * 256 + threadIdx.x;
    const float* xb = x + (size_t)b * DS + n;
    const float* mb = MT + (size_t)b * 16384;
    float acc[128];
#pragma unroll
    for (int m = 0; m < 128; ++m) acc[m] = proj_b[m];
#pragma unroll 2
    for (int c = 0; c < 128; ++c) {
        float xv = xb[(size_t)c * N_SP];
        const float* mr = mb + c * 128;
#pragma unroll
        for (int m = 0; m < 128; ++m) acc[m] = fmaf(mr[m], xv, acc[m]);
    }
    float* ob = xout + (size_t)b * DS + n;
    float s = 0.f, sq = 0.f;
#pragma unroll
    for (int m = 0; m < 128; ++m) {
        float v = acc[m];
        ob[(size_t)m * N_SP] = v;
        s += v; sq = fmaf(v, v, sq);
    }
#pragma unroll
    for (int off = 32; off > 0; off >>= 1) {
        s += __shfl_down(s, off, 64);
        sq += __shfl_down(sq, off, 64);
    }
    if ((threadIdx.x & 63) == 0) {
        atomicAdd(&st[0 + b], s);
        atomicAdd(&st[8 + b], sq);
    }
}

// ---------- LN stats finalize ----------
__global__ void k_finalize(float* st, int off) {
    int b = threadIdx.x;
    if (b < 8) {
        const float invn = 1.0f / 4194304.0f;   // C*N
        float mu = st[off + b] * invn;
        float var = st[off + 8 + b] * invn - mu * mu;
        st[off + 16 + b] = mu;
        st[off + 24 + b] = rsqrtf(var + 1e-5f);
    }
}

// ---------- LN apply in-place (per-element affine) ----------
__global__ __launch_bounds__(256) void k_lnapply(const float* __restrict__ in,
                                                 const float* __restrict__ lnw,
                                                 const float* __restrict__ lnb,
                                                 const float* __restrict__ st, int off,
                                                 float* __restrict__ out) {
    size_t i4 = (size_t)blockIdx.x * 256 + threadIdx.x;
    int b = (int)(i4 >> 20);                  // 2^20 float4 per batch
    size_t cn = i4 * 4 - (size_t)b * 4194304;
    float mu = st[off + 16 + b], rs = st[off + 24 + b];
    const float4 xv = *(const float4*)(in + (size_t)b * DS + cn);
    const float4 wv = *(const float4*)(lnw + cn);
    const float4 bv = *(const float4*)(lnb + cn);
    float4 o;
    o.x = (xv.x - mu) * rs * wv.x + bv.x;
    o.y = (xv.y - mu) * rs * wv.y + bv.y;
    o.z = (xv.z - mu) * rs * wv.z + bv.z;
    o.w = (xv.w - mu) * rs * wv.w + bv.w;
    *(float4*)(out + (size_t)b * DS + cn) = o;
}

// ---------- fused MLP in-place: x2pre = x1 + b2 + W2 gelu(W1 x1 + b1), LN2 stats ----------
__global__ __launch_bounds__(256, 1) void k_mlp(float* __restrict__ xio,
                                                const float* __restrict__ w1,
                                                const float* __restrict__ b1v,
                                                const float* __restrict__ w2T,
                                                const float* __restrict__ b2v,
                                                float* __restrict__ st) {
    const int b = blockIdx.y;
    const int n = blockIdx.x * 256 + threadIdx.x;
    float* xb = xio + (size_t)b * DS + n;
    float xcol[128];
#pragma unroll
    for (int c = 0; c < 128; ++c) xcol[c] = xb[(size_t)c * N_SP];
    float acc[128];
#pragma unroll
    for (int m = 0; m < 128; ++m) acc[m] = b2v[m] + xcol[m];   // residual + bias
#pragma unroll 1
    for (int o = 0; o < 512; o += 2) {
        const float* w1a = w1 + (size_t)o * 128;
        const float* w1b = w1a + 128;
        float s0 = 0.f, s1 = 0.f, s2 = 0.f, s3 = 0.f;
        float r0 = 0.f, r1 = 0.f, r2 = 0.f, r3 = 0.f;
#pragma unroll
        for (int c = 0; c < 128; c += 4) {
            s0 = fmaf(w1a[c], xcol[c], s0);
            s1 = fmaf(w1a[c + 1], xcol[c + 1], s1);
            s2 = fmaf(w1a[c + 2], xcol[c + 2], s2);
            s3 = fmaf(w1a[c + 3], xcol[c + 3], s3);
            r0 = fmaf(w1b[c], xcol[c], r0);
            r1 = fmaf(w1b[c + 1], xcol[c + 1], r1);
            r2 = fmaf(w1b[c + 2], xcol[c + 2], r2);
            r3 = fmaf(w1b[c + 3], xcol[c + 3], r3);
        }
        float h0 = (s0 + s1) + (s2 + s3) + b1v[o];
        float h1 = (r0 + r1) + (r2 + r3) + b1v[o + 1];
        float g0 = 0.5f * h0 * (1.0f + erff(h0 * 0.70710678118654752f));
        float g1 = 0.5f * h1 * (1.0f + erff(h1 * 0.70710678118654752f));
        const float* wa = w2T + (size_t)o * 128;
        const float* wb = wa + 128;
#pragma unroll
        for (int m = 0; m < 128; ++m)
            acc[m] = fmaf(wb[m], g1, fmaf(wa[m], g0, acc[m]));
    }
    float s = 0.f, sq = 0.f;
#pragma unroll
    for (int m = 0; m < 128; ++m) {
        float v = acc[m];
        xb[(size_t)m * N_SP] = v;
        s += v; sq = fmaf(v, v, sq);
    }
#pragma unroll
    for (int off = 32; off > 0; off >>= 1) {
        s += __shfl_down(s, off, 64);
        sq += __shfl_down(sq, off, 64);
    }
    if ((threadIdx.x & 63) == 0) {
        atomicAdd(&st[32 + b], s);
        atomicAdd(&st[40 + b], sq);
    }
}

extern "C" void kernel_launch(void* const* d_in, const int* in_sizes, int n_in,
                              void* d_out, int out_size, void* d_ws, size_t ws_size,
                              hipStream_t stream) {
    const float* x      = (const float*)d_in[0];
    const float* qkv_w  = (const float*)d_in[1];
    const float* proj_w = (const float*)d_in[2];
    const float* proj_b = (const float*)d_in[3];
    const float* ln1_w  = (const float*)d_in[4];
    const float* ln1_b  = (const float*)d_in[5];
    const float* ln2_w  = (const float*)d_in[6];
    const float* ln2_b  = (const float*)d_in[7];
    const float* mlp_w1 = (const float*)d_in[8];
    const float* mlp_b1 = (const float*)d_in[9];
    const float* mlp_w2 = (const float*)d_in[10];
    const float* mlp_b2 = (const float*)d_in[11];
    float* out = (float*)d_out;

    // workspace (floats), total ~35 MB
    float* ws    = (float*)d_ws;
    float* Gpart = ws;                    // 8*64*16384 = 8,388,608
    float* G     = ws + 8388608;          // 131072
    float* attn  = G + 131072;            // 16384
    float* MT    = attn + 16384;          // 131072
    float* st    = MT + 131072;           // 64
    float* PT    = st + 64;               // 16384  (proj_w^T)
    float* w2T   = PT + 16384;            // 65536  (mlp_w2^T: [512][128])

    hipMemsetAsync(st, 0, 64 * sizeof(float), stream);

    k_transpose<<<64, 256, 0, stream>>>(proj_w, PT, 128, 128);
    k_transpose<<<256, 256, 0, stream>>>(mlp_w2, w2T, 128, 512);

    k_cov<<<dim3(64, 8), 256, 0, stream>>>(x, Gpart);
    k_greduce<<<512, 256, 0, stream>>>(Gpart, G);
    k_gram_small<<<64, 256, 0, stream>>>(G, qkv_w, attn);
    k_mfold<<<8, 256, 0, stream>>>(attn, qkv_w, PT, MT);

    k_attnproj<<<dim3(128, 8), 256, 0, stream>>>(x, MT, proj_b, out, st);
    k_finalize<<<1, 64, 0, stream>>>(st, 0);
    k_lnapply<<<32768, 256, 0, stream>>>(out, ln1_w, ln1_b, st, 0, out);

    k_mlp<<<dim3(128, 8), 256, 0, stream>>>(out, mlp_w1, mlp_b1, w2T, mlp_b2, st);
    k_finalize<<<1, 64, 0, stream>>>(st, 32);
    k_lnapply<<<32768, 256, 0, stream>>>(out, ln2_w, ln2_b, st, 32, out);
}

// Round 3
// 1809.820 us; speedup vs baseline: 3.4347x; 3.4347x over previous
//
#include <hip/hip_runtime.h>
#include <hip/hip_bf16.h>
#include <math.h>

// TransformerBlock3D: B=8, C=128, S=32 (N=32768), HEADS=8 (dim_head=16), MLP=512
// Round 3: bf16 MFMA for the two big GEMMs.
//  - attention collapsed: G = X X^T, attn = softmax(Wq G Wk^T * 0.25),
//    Mb = proj_w . blockdiag(attn) . Wv  (bf16, NO identity -> residual added fp32)
//  - k_attnproj: x1pre = Mb x + proj_b + x   via mfma_f32_16x16x32_bf16
//  - k_mlp: fused W2 gelu(W1 x1 + b1) + b2 + x1, hid kept in LDS (bf16), never HBM
//  - d_out is the activation buffer (in-place LN / MLP); d_ws ~33 MB.

#define N_SP 32768
typedef __hip_bfloat16 bf16;
static const size_t DS = (size_t)128 * N_SP;

typedef __attribute__((ext_vector_type(8))) short s8b;   // 8 bf16 (4 VGPRs)
typedef __attribute__((ext_vector_type(4))) short s4b;   // 4 bf16
typedef __attribute__((ext_vector_type(4))) float f4;    // mfma acc

__device__ __forceinline__ ushort f2b(float f) {
    __hip_bfloat16 h = __float2bfloat16(f);
    return *reinterpret_cast<ushort*>(&h);
}

// tanh-form GELU: g = h * (1 - 1/(exp(2w)+1)), w = 0.79788456*h*(1+0.044715h^2)
__device__ __forceinline__ float gelu_f(float h) {
    float u = 1.5957691216057308f * h * fmaf(0.044715f, h * h, 1.0f);
    float e = __expf(u);
    return h * (1.0f - __builtin_amdgcn_rcpf(e + 1.0f));
}

// ---------- tiny transpose: out[c*R + r] = in[r*C + c] ----------
__global__ __launch_bounds__(256) void k_transpose(const float* __restrict__ in,
                                                   float* __restrict__ out,
                                                   int R, int Ccols) {
    int idx = blockIdx.x * 256 + threadIdx.x;
    if (idx >= R * Ccols) return;
    int r = idx / Ccols, c = idx % Ccols;
    out[c * R + r] = in[idx];
}

// ---------- fp32 -> bf16 convert ----------
__global__ __launch_bounds__(256) void k_cvt(const float* __restrict__ in,
                                             ushort* __restrict__ out, int n) {
    int i = blockIdx.x * 256 + threadIdx.x;
    if (i < n) out[i] = f2b(in[i]);
}

// ---------- covariance partials: Gpart[b*64+kb][i][j] = sum_{n slice} x_i x_j ----------
__global__ __launch_bounds__(256) void k_cov(const float* __restrict__ x,
                                             float* __restrict__ Gpart) {
    __shared__ __align__(16) float xs[64 * 132];
    const int kb = blockIdx.x, b = blockIdx.y;
    const int t = threadIdx.x;
    const int i0 = (t >> 4) * 8, j0 = (t & 15) * 8;
    float acc[64];
#pragma unroll
    for (int k = 0; k < 64; ++k) acc[k] = 0.f;
    const float* xb = x + (size_t)b * DS;
    for (int sub = 0; sub < 8; ++sub) {
        const int n0 = kb * 512 + sub * 64;
        __syncthreads();
#pragma unroll
        for (int r = 0; r < 32; ++r) {
            int id = r * 256 + t;
            int c = id >> 6, nn = id & 63;
            xs[nn * 132 + c] = xb[(size_t)c * N_SP + n0 + nn];
        }
        __syncthreads();
#pragma unroll 4
        for (int nn = 0; nn < 64; ++nn) {
            float av[8], bv[8];
            *(float4*)&av[0] = *(const float4*)&xs[nn * 132 + i0];
            *(float4*)&av[4] = *(const float4*)&xs[nn * 132 + i0 + 4];
            *(float4*)&bv[0] = *(const float4*)&xs[nn * 132 + j0];
            *(float4*)&bv[4] = *(const float4*)&xs[nn * 132 + j0 + 4];
#pragma unroll
            for (int ii = 0; ii < 8; ++ii)
#pragma unroll
                for (int jj = 0; jj < 8; ++jj)
                    acc[ii * 8 + jj] = fmaf(av[ii], bv[jj], acc[ii * 8 + jj]);
        }
    }
    float* gp = Gpart + ((size_t)b * 64 + kb) * 16384;
#pragma unroll
    for (int ii = 0; ii < 8; ++ii)
#pragma unroll
        for (int jj = 0; jj < 8; jj += 4) {
            float4 v = make_float4(acc[ii * 8 + jj], acc[ii * 8 + jj + 1],
                                   acc[ii * 8 + jj + 2], acc[ii * 8 + jj + 3]);
            *(float4*)&gp[(i0 + ii) * 128 + j0 + jj] = v;
        }
}

__global__ __launch_bounds__(256) void k_greduce(const float* __restrict__ Gpart,
                                                 float* __restrict__ G) {
    int tid = blockIdx.x * 256 + threadIdx.x;
    int b = tid >> 14, ij = tid & 16383;
    float s = 0.f;
    for (int kb = 0; kb < 64; ++kb)
        s += Gpart[((size_t)b * 64 + kb) * 16384 + ij];
    G[tid] = s;
}

// ---------- gram + softmax ----------
__global__ __launch_bounds__(256) void k_gram_small(const float* __restrict__ G,
                                                    const float* __restrict__ qkv_w,
                                                    float* __restrict__ attn) {
    __shared__ float t1[16 * 132];
    __shared__ float sg[16 * 16];
    const int bh = blockIdx.x;
    const int b = bh >> 3, h = bh & 7;
    const int t = threadIdx.x;
    {
        const int i = t >> 4, c20 = (t & 15) * 8;
        const float* wq = qkv_w + (size_t)(h * 16 + i) * 128;
        const float* Gb = G + (size_t)b * 16384;
        float a[8];
#pragma unroll
        for (int k = 0; k < 8; ++k) a[k] = 0.f;
        for (int c = 0; c < 128; ++c) {
            float w = wq[c];
            const float* grow = Gb + c * 128 + c20;
#pragma unroll
            for (int k = 0; k < 8; ++k) a[k] = fmaf(w, grow[k], a[k]);
        }
#pragma unroll
        for (int k = 0; k < 8; ++k) t1[i * 132 + c20 + k] = a[k];
    }
    __syncthreads();
    {
        const int i = t >> 4, j = t & 15;
        const float* wk = qkv_w + (size_t)(128 + h * 16 + j) * 128;
        float s = 0.f;
        for (int c2 = 0; c2 < 128; ++c2) s = fmaf(t1[i * 132 + c2], wk[c2], s);
        sg[i * 16 + j] = s * 0.25f;
    }
    __syncthreads();
    if (t < 16) {
        float mx = -1e30f;
#pragma unroll
        for (int j = 0; j < 16; ++j) mx = fmaxf(mx, sg[t * 16 + j]);
        float e[16], sum = 0.f;
#pragma unroll
        for (int j = 0; j < 16; ++j) { e[j] = expf(sg[t * 16 + j] - mx); sum += e[j]; }
        float inv = 1.0f / sum;
#pragma unroll
        for (int j = 0; j < 16; ++j)
            attn[((size_t)bh * 16 + t) * 16 + j] = e[j] * inv;
    }
}

// ---------- fold: Mbb[b][o][c] = bf16( (P . blockdiag(attn) . Wv)[o][c] )  (no +I) ----------
__global__ __launch_bounds__(256, 2) void k_mfold(const float* __restrict__ attn,
                                                  const float* __restrict__ qkv_w,
                                                  const float* __restrict__ PT,
                                                  ushort* __restrict__ Mbb) {
    __shared__ float t2[128 * 128];   // 64 KB
    const int b = blockIdx.x, t = threadIdx.x;
    {
        const int hi = t >> 1, c0 = (t & 1) * 64;
        const int h = hi >> 4;
        const float* at = attn + ((size_t)b * 128 + hi) * 16;
        float a[16];
#pragma unroll
        for (int j = 0; j < 16; ++j) a[j] = at[j];
        float sc[64];
#pragma unroll
        for (int c = 0; c < 64; ++c) sc[c] = 0.f;
        for (int j = 0; j < 16; ++j) {
            const float* wv = qkv_w + (size_t)(256 + h * 16 + j) * 128 + c0;
            float aj = a[j];
#pragma unroll
            for (int c = 0; c < 64; ++c) sc[c] = fmaf(aj, wv[c], sc[c]);
        }
#pragma unroll
        for (int c = 0; c < 64; ++c) t2[hi * 128 + c0 + c] = sc[c];
    }
    __syncthreads();
    const int c = t & 127, half = t >> 7;
    float acc[128];
#pragma unroll
    for (int o = 0; o < 128; ++o) acc[o] = 0.f;
    for (int ci = half * 64; ci < half * 64 + 64; ++ci) {
        float s = t2[ci * 128 + c];
        const float* pt = PT + ci * 128;
#pragma unroll
        for (int o = 0; o < 128; ++o) acc[o] = fmaf(pt[o], s, acc[o]);
    }
    __syncthreads();
    if (half) {
#pragma unroll
        for (int o = 0; o < 128; ++o) t2[c * 128 + o] = acc[o];
    }
    __syncthreads();
    if (!half) {
        ushort* m = Mbb + (size_t)b * 16384;
#pragma unroll
        for (int o = 0; o < 128; ++o)
            m[(size_t)o * 128 + c] = f2b(acc[o] + t2[c * 128 + o]);
    }
}

// ---------- MFMA attnproj: x1pre = Mb x + proj_b + x, LN1 stats ----------
// block: 256 thr (4 waves), tile = 64 n-cols of batch b. Wave w: M=128 x N=16.
__global__ __launch_bounds__(256, 4) void k_attnproj(const float* __restrict__ x,
                                                     const ushort* __restrict__ Mbb,
                                                     const float* __restrict__ proj_b,
                                                     float* __restrict__ xout,
                                                     float* __restrict__ st) {
    __shared__ ushort xT[64 * 140];   // [n][c] bf16, stride 140 (8B-aligned rows)
    const int b = blockIdx.y;
    const int n0 = blockIdx.x * 64;
    const int t = threadIdx.x;
    {   // stage: lanes span n (coalesced), each thread 32 c's
        const int n = t & 63, cg = t >> 6;
        const float* xp = x + (size_t)b * DS + n0 + n;
#pragma unroll
        for (int cc = 0; cc < 32; ++cc) {
            int c = cg * 32 + cc;
            xT[n * 140 + c] = f2b(xp[(size_t)c * N_SP]);
        }
    }
    __syncthreads();
    const int wave = t >> 6, lane = t & 63;
    const int q = lane >> 4, r = lane & 15;
    const ushort* mb = Mbb + (size_t)b * 16384;
    f4 acc[8];
#pragma unroll
    for (int m = 0; m < 8; ++m) acc[m] = (f4){0.f, 0.f, 0.f, 0.f};
    const ushort* xr = &xT[(wave * 16 + r) * 140 + q * 8];
#pragma unroll
    for (int kk = 0; kk < 4; ++kk) {
        s4b blo = *(const s4b*)(xr + kk * 32);
        s4b bhi = *(const s4b*)(xr + kk * 32 + 4);
        s8b bfrag = __builtin_shufflevector(blo, bhi, 0, 1, 2, 3, 4, 5, 6, 7);
#pragma unroll
        for (int m = 0; m < 8; ++m) {
            s8b afrag = *(const s8b*)(mb + (size_t)(m * 16 + r) * 128 + kk * 32 + q * 8);
            acc[m] = __builtin_amdgcn_mfma_f32_16x16x32_bf16(afrag, bfrag, acc[m], 0, 0, 0);
        }
    }
    // epilogue: D[m][n]: m = mfrag*16 + q*4 + reg, n = lane&15 (+wave*16)
    const int nn = n0 + wave * 16 + r;
    const float* xres = x + (size_t)b * DS + nn;
    float* op = xout + (size_t)b * DS + nn;
    float s = 0.f, sq = 0.f;
#pragma unroll
    for (int m = 0; m < 8; ++m)
#pragma unroll
        for (int rg = 0; rg < 4; ++rg) {
            int mm = m * 16 + q * 4 + rg;
            float val = acc[m][rg] + proj_b[mm] + xres[(size_t)mm * N_SP];
            op[(size_t)mm * N_SP] = val;
            s += val; sq = fmaf(val, val, sq);
        }
#pragma unroll
    for (int off = 32; off > 0; off >>= 1) {
        s += __shfl_down(s, off, 64);
        sq += __shfl_down(sq, off, 64);
    }
    if (lane == 0) {
        atomicAdd(&st[0 + b], s);
        atomicAdd(&st[8 + b], sq);
    }
}

// ---------- LN stats finalize ----------
__global__ void k_finalize(float* st, int off) {
    int b = threadIdx.x;
    if (b < 8) {
        const float invn = 1.0f / 4194304.0f;
        float mu = st[off + b] * invn;
        float var = st[off + 8 + b] * invn - mu * mu;
        st[off + 16 + b] = mu;
        st[off + 24 + b] = rsqrtf(var + 1e-5f);
    }
}

// ---------- LN apply in-place ----------
__global__ __launch_bounds__(256) void k_lnapply(const float* __restrict__ in,
                                                 const float* __restrict__ lnw,
                                                 const float* __restrict__ lnb,
                                                 const float* __restrict__ st, int off,
                                                 float* __restrict__ out) {
    size_t i4 = (size_t)blockIdx.x * 256 + threadIdx.x;
    int b = (int)(i4 >> 20);
    size_t cn = i4 * 4 - (size_t)b * 4194304;
    float mu = st[off + 16 + b], rs = st[off + 24 + b];
    const float4 xv = *(const float4*)(in + (size_t)b * DS + cn);
    const float4 wv = *(const float4*)(lnw + cn);
    const float4 bv = *(const float4*)(lnb + cn);
    float4 o;
    o.x = (xv.x - mu) * rs * wv.x + bv.x;
    o.y = (xv.y - mu) * rs * wv.y + bv.y;
    o.z = (xv.z - mu) * rs * wv.z + bv.z;
    o.w = (xv.w - mu) * rs * wv.w + bv.w;
    *(float4*)(out + (size_t)b * DS + cn) = o;
}

// ---------- fused MFMA MLP: x2pre = x1 + b2 + W2 gelu(W1 x1 + b1), LN2 stats ----------
// block: 256 thr, tile = 64 n-cols. Loop over 4 o-slices of 128:
//   phase1 mfma (W1 slice) -> gelu -> bf16 -> hT LDS -> phase2 mfma (W2 slice) accumulate.
__global__ __launch_bounds__(256, 3) void k_mlp(float* __restrict__ xio,
                                                const ushort* __restrict__ w1b,
                                                const float* __restrict__ b1v,
                                                const ushort* __restrict__ w2b,
                                                const float* __restrict__ b2v,
                                                float* __restrict__ st) {
    __shared__ ushort xT[64 * 140];   // [n][c]
    __shared__ ushort hT[64 * 136];   // [n][o_slice]
    const int b = blockIdx.y;
    const int n0 = blockIdx.x * 64;
    const int t = threadIdx.x;
    {
        const int n = t & 63, cg = t >> 6;
        const float* xp = xio + (size_t)b * DS + n0 + n;
#pragma unroll
        for (int cc = 0; cc < 32; ++cc) {
            int c = cg * 32 + cc;
            xT[n * 140 + c] = f2b(xp[(size_t)c * N_SP]);
        }
    }
    __syncthreads();
    const int wave = t >> 6, lane = t & 63;
    const int q = lane >> 4, r = lane & 15;
    const ushort* xr = &xT[(wave * 16 + r) * 140 + q * 8];
    ushort* hrow = &hT[(wave * 16 + r) * 136];
    f4 acc2[8];
#pragma unroll
    for (int m = 0; m < 8; ++m) acc2[m] = (f4){0.f, 0.f, 0.f, 0.f};

    for (int os = 0; os < 4; ++os) {
        f4 acc1[8];
#pragma unroll
        for (int m = 0; m < 8; ++m) acc1[m] = (f4){0.f, 0.f, 0.f, 0.f};
#pragma unroll
        for (int kk = 0; kk < 4; ++kk) {
            s4b blo = *(const s4b*)(xr + kk * 32);
            s4b bhi = *(const s4b*)(xr + kk * 32 + 4);
            s8b bfrag = __builtin_shufflevector(blo, bhi, 0, 1, 2, 3, 4, 5, 6, 7);
#pragma unroll
            for (int m = 0; m < 8; ++m) {
                s8b afrag = *(const s8b*)(w1b + (size_t)(os * 128 + m * 16 + r) * 128
                                          + kk * 32 + q * 8);
                acc1[m] = __builtin_amdgcn_mfma_f32_16x16x32_bf16(afrag, bfrag, acc1[m], 0, 0, 0);
            }
        }
        __syncthreads();   // previous slice's hT reads done
#pragma unroll
        for (int m = 0; m < 8; ++m) {
            ushort4 pk;
            float h0 = acc1[m][0] + b1v[os * 128 + m * 16 + q * 4 + 0];
            float h1 = acc1[m][1] + b1v[os * 128 + m * 16 + q * 4 + 1];
            float h2 = acc1[m][2] + b1v[os * 128 + m * 16 + q * 4 + 2];
            float h3 = acc1[m][3] + b1v[os * 128 + m * 16 + q * 4 + 3];
            pk.x = f2b(gelu_f(h0)); pk.y = f2b(gelu_f(h1));
            pk.z = f2b(gelu_f(h2)); pk.w = f2b(gelu_f(h3));
            *(ushort4*)(hrow + m * 16 + q * 4) = pk;
        }
        __syncthreads();
#pragma unroll
        for (int kk = 0; kk < 4; ++kk) {
            s8b hfrag = *(const s8b*)(hrow + kk * 32 + q * 8);
#pragma unroll
            for (int m = 0; m < 8; ++m) {
                s8b afrag = *(const s8b*)(w2b + (size_t)(m * 16 + r) * 512
                                          + os * 128 + kk * 32 + q * 8);
                acc2[m] = __builtin_amdgcn_mfma_f32_16x16x32_bf16(afrag, hfrag, acc2[m], 0, 0, 0);
            }
        }
    }
    // epilogue: residual (fp32 reload) + bias + stats, write in-place
    const int nn = n0 + wave * 16 + r;
    float* op = xio + (size_t)b * DS + nn;
    float s = 0.f, sq = 0.f;
#pragma unroll
    for (int m = 0; m < 8; ++m)
#pragma unroll
        for (int rg = 0; rg < 4; ++rg) {
            int mm = m * 16 + q * 4 + rg;
            float val = acc2[m][rg] + b2v[mm] + op[(size_t)mm * N_SP];
            op[(size_t)mm * N_SP] = val;
            s += val; sq = fmaf(val, val, sq);
        }
#pragma unroll
    for (int off = 32; off > 0; off >>= 1) {
        s += __shfl_down(s, off, 64);
        sq += __shfl_down(sq, off, 64);
    }
    if (lane == 0) {
        atomicAdd(&st[32 + b], s);
        atomicAdd(&st[40 + b], sq);
    }
}

extern "C" void kernel_launch(void* const* d_in, const int* in_sizes, int n_in,
                              void* d_out, int out_size, void* d_ws, size_t ws_size,
                              hipStream_t stream) {
    const float* x      = (const float*)d_in[0];
    const float* qkv_w  = (const float*)d_in[1];
    const float* proj_w = (const float*)d_in[2];
    const float* proj_b = (const float*)d_in[3];
    const float* ln1_w  = (const float*)d_in[4];
    const float* ln1_b  = (const float*)d_in[5];
    const float* ln2_w  = (const float*)d_in[6];
    const float* ln2_b  = (const float*)d_in[7];
    const float* mlp_w1 = (const float*)d_in[8];
    const float* mlp_b1 = (const float*)d_in[9];
    const float* mlp_w2 = (const float*)d_in[10];
    const float* mlp_b2 = (const float*)d_in[11];
    float* out = (float*)d_out;

    // workspace layout (bytes), total ~33.1 MB
    char* wsb = (char*)d_ws;
    float*  Gpart = (float*)wsb;                      // 33,554,432 B
    float*  G     = (float*)(wsb + 33554432);         // 524,288
    float*  attn  = (float*)(wsb + 34078720);         // 65,536
    float*  PT    = (float*)(wsb + 34144256);         // 65,536
    float*  st    = (float*)(wsb + 34209792);         // 256
    ushort* Mbb   = (ushort*)(wsb + 34210048);        // 262,144
    ushort* w1b   = (ushort*)(wsb + 34472192);        // 131,072
    ushort* w2b   = (ushort*)(wsb + 34603264);        // 131,072

    hipMemsetAsync(st, 0, 64 * sizeof(float), stream);

    k_transpose<<<64, 256, 0, stream>>>(proj_w, PT, 128, 128);
    k_cvt<<<256, 256, 0, stream>>>(mlp_w1, w1b, 65536);   // [512][128] row-major = A[m][k]
    k_cvt<<<256, 256, 0, stream>>>(mlp_w2, w2b, 65536);   // [128][512] row-major = A[m][k]

    k_cov<<<dim3(64, 8), 256, 0, stream>>>(x, Gpart);
    k_greduce<<<512, 256, 0, stream>>>(Gpart, G);
    k_gram_small<<<64, 256, 0, stream>>>(G, qkv_w, attn);
    k_mfold<<<8, 256, 0, stream>>>(attn, qkv_w, PT, Mbb);

    k_attnproj<<<dim3(512, 8), 256, 0, stream>>>(x, Mbb, proj_b, out, st);
    k_finalize<<<1, 64, 0, stream>>>(st, 0);
    k_lnapply<<<32768, 256, 0, stream>>>(out, ln1_w, ln1_b, st, 0, out);

    k_mlp<<<dim3(512, 8), 256, 0, stream>>>(out, w1b, mlp_b1, w2b, mlp_b2, st);
    k_finalize<<<1, 64, 0, stream>>>(st, 32);
    k_lnapply<<<32768, 256, 0, stream>>>(out, ln2_w, ln2_b, st, 32, out);
}

// Round 4
// 1269.459 us; speedup vs baseline: 4.8967x; 1.4257x over previous
//
#include <hip/hip_runtime.h>
#include <hip/hip_bf16.h>
#include <math.h>

// TransformerBlock3D: B=8, C=128, S=32 (N=32768), HEADS=8 (dim_head=16), MLP=512
// Round 4: latency fix for MFMA kernels (round 3: MfmaUtil 3.97%, 1:1 MFMA:load).
//  - 128-col tiles, N=32/wave: each weight A-frag feeds 2 MFMAs, 64 MFMAs/barrier.
//  - k_mlp: LN1-apply fused into staging (lnapply1 kernel deleted); xT/hT in
//    XOR-swizzled 64KB LDS; residual from bf16 LDS.
//  - k_cov converted to bf16 MFMA.
// Math: G=XX^T, attn=softmax(0.25*WqGWk^T), Mb=P.blockdiag(attn).Wv (bf16),
//       x1pre = Mb x + proj_b + x; x1 = LN1(x1pre); x2pre = x1 + b2 + W2 gelu(W1 x1 + b1).

#define N_SP 32768
typedef __hip_bfloat16 bf16;
static const size_t DS = (size_t)128 * N_SP;

typedef __attribute__((ext_vector_type(8))) short s8b;
typedef __attribute__((ext_vector_type(4))) float f4;

__device__ __forceinline__ ushort f2b(float f) {
    __hip_bfloat16 h = __float2bfloat16(f);
    return *reinterpret_cast<ushort*>(&h);
}
__device__ __forceinline__ float b2f(ushort u) {
    unsigned v = ((unsigned)u) << 16;
    float f;
    __builtin_memcpy(&f, &v, 4);
    return f;
}
__device__ __forceinline__ float gelu_f(float h) {
    float u = 1.5957691216057308f * h * fmaf(0.044715f, h * h, 1.0f);
    float e = __expf(u);
    return h * (1.0f - __builtin_amdgcn_rcpf(e + 1.0f));
}
// swizzled index for 128-col bf16 LDS tiles (c0 multiple of 8)
__device__ __forceinline__ int swz8(int n, int c0) {
    return n * 128 + (c0 ^ ((n & 15) << 3));
}
// swizzled index, c0 multiple of 4
__device__ __forceinline__ int swz4(int n, int c0) {
    return n * 128 + (((c0 & 0x78) ^ ((n & 15) << 3)) | (c0 & 4));
}

// ---------- tiny transpose ----------
__global__ __launch_bounds__(256) void k_transpose(const float* __restrict__ in,
                                                   float* __restrict__ out,
                                                   int R, int Ccols) {
    int idx = blockIdx.x * 256 + threadIdx.x;
    if (idx >= R * Ccols) return;
    int r = idx / Ccols, c = idx % Ccols;
    out[c * R + r] = in[idx];
}

// ---------- fp32 -> bf16 ----------
__global__ __launch_bounds__(256) void k_cvt(const float* __restrict__ in,
                                             ushort* __restrict__ out, int n) {
    int i = blockIdx.x * 256 + threadIdx.x;
    if (i < n) out[i] = f2b(in[i]);
}

// ---------- covariance partials via MFMA: Gpart[b*64+kb] = X Xs^T over 512 n ----------
__global__ __launch_bounds__(256, 3) void k_cov(const float* __restrict__ x,
                                                float* __restrict__ Gpart) {
    __shared__ ushort xs[128 * 136];   // [c][n_local], pad 136
    const int kb = blockIdx.x, b = blockIdx.y;
    const int t = threadIdx.x;
    const int wave = t >> 6, lane = t & 63, q = lane >> 4, r = lane & 15;
    f4 acc[8][2];
#pragma unroll
    for (int m = 0; m < 8; ++m) { acc[m][0] = (f4){0,0,0,0}; acc[m][1] = (f4){0,0,0,0}; }
    for (int ch = 0; ch < 4; ++ch) {
        const int nbase = kb * 512 + ch * 128;
        __syncthreads();
        {
            const int nn = t & 127, cg = t >> 7;
            const float* xp = x + (size_t)b * DS + nbase + nn;
#pragma unroll
            for (int cc = 0; cc < 64; ++cc) {
                int c = cg * 64 + cc;
                xs[c * 136 + nn] = f2b(xp[(size_t)c * N_SP]);
            }
        }
        __syncthreads();
#pragma unroll
        for (int kk = 0; kk < 4; ++kk) {
            const int c0 = kk * 32 + q * 8;
            s8b bj0 = *(const s8b*)&xs[(wave * 32 + r) * 136 + c0];
            s8b bj1 = *(const s8b*)&xs[(wave * 32 + 16 + r) * 136 + c0];
#pragma unroll
            for (int m = 0; m < 8; ++m) {
                s8b a = *(const s8b*)&xs[(m * 16 + r) * 136 + c0];
                acc[m][0] = __builtin_amdgcn_mfma_f32_16x16x32_bf16(a, bj0, acc[m][0], 0, 0, 0);
                acc[m][1] = __builtin_amdgcn_mfma_f32_16x16x32_bf16(a, bj1, acc[m][1], 0, 0, 0);
            }
        }
    }
    float* gp = Gpart + ((size_t)b * 64 + kb) * 16384;
#pragma unroll
    for (int n2 = 0; n2 < 2; ++n2)
#pragma unroll
        for (int m = 0; m < 8; ++m)
#pragma unroll
            for (int rg = 0; rg < 4; ++rg) {
                int i = m * 16 + q * 4 + rg;
                int j = wave * 32 + n2 * 16 + r;
                gp[i * 128 + j] = acc[m][n2][rg];
            }
}

__global__ __launch_bounds__(256) void k_greduce(const float* __restrict__ Gpart,
                                                 float* __restrict__ G) {
    int tid = blockIdx.x * 256 + threadIdx.x;
    int b = tid >> 14, ij = tid & 16383;
    float s = 0.f;
    for (int kb = 0; kb < 64; ++kb)
        s += Gpart[((size_t)b * 64 + kb) * 16384 + ij];
    G[tid] = s;
}

// ---------- gram + softmax ----------
__global__ __launch_bounds__(256) void k_gram_small(const float* __restrict__ G,
                                                    const float* __restrict__ qkv_w,
                                                    float* __restrict__ attn) {
    __shared__ float t1[16 * 132];
    __shared__ float sg[16 * 16];
    const int bh = blockIdx.x;
    const int b = bh >> 3, h = bh & 7;
    const int t = threadIdx.x;
    {
        const int i = t >> 4, c20 = (t & 15) * 8;
        const float* wq = qkv_w + (size_t)(h * 16 + i) * 128;
        const float* Gb = G + (size_t)b * 16384;
        float a[8];
#pragma unroll
        for (int k = 0; k < 8; ++k) a[k] = 0.f;
        for (int c = 0; c < 128; ++c) {
            float w = wq[c];
            const float* grow = Gb + c * 128 + c20;
#pragma unroll
            for (int k = 0; k < 8; ++k) a[k] = fmaf(w, grow[k], a[k]);
        }
#pragma unroll
        for (int k = 0; k < 8; ++k) t1[i * 132 + c20 + k] = a[k];
    }
    __syncthreads();
    {
        const int i = t >> 4, j = t & 15;
        const float* wk = qkv_w + (size_t)(128 + h * 16 + j) * 128;
        float s = 0.f;
        for (int c2 = 0; c2 < 128; ++c2) s = fmaf(t1[i * 132 + c2], wk[c2], s);
        sg[i * 16 + j] = s * 0.25f;
    }
    __syncthreads();
    if (t < 16) {
        float mx = -1e30f;
#pragma unroll
        for (int j = 0; j < 16; ++j) mx = fmaxf(mx, sg[t * 16 + j]);
        float e[16], sum = 0.f;
#pragma unroll
        for (int j = 0; j < 16; ++j) { e[j] = expf(sg[t * 16 + j] - mx); sum += e[j]; }
        float inv = 1.0f / sum;
#pragma unroll
        for (int j = 0; j < 16; ++j)
            attn[((size_t)bh * 16 + t) * 16 + j] = e[j] * inv;
    }
}

// ---------- fold: Mbb[b][o][c] = bf16( (P . blockdiag(attn) . Wv)[o][c] ) ----------
__global__ __launch_bounds__(256, 2) void k_mfold(const float* __restrict__ attn,
                                                  const float* __restrict__ qkv_w,
                                                  const float* __restrict__ PT,
                                                  ushort* __restrict__ Mbb) {
    __shared__ float t2[128 * 128];
    const int b = blockIdx.x, t = threadIdx.x;
    {
        const int hi = t >> 1, c0 = (t & 1) * 64;
        const int h = hi >> 4;
        const float* at = attn + ((size_t)b * 128 + hi) * 16;
        float a[16];
#pragma unroll
        for (int j = 0; j < 16; ++j) a[j] = at[j];
        float sc[64];
#pragma unroll
        for (int c = 0; c < 64; ++c) sc[c] = 0.f;
        for (int j = 0; j < 16; ++j) {
            const float* wv = qkv_w + (size_t)(256 + h * 16 + j) * 128 + c0;
            float aj = a[j];
#pragma unroll
            for (int c = 0; c < 64; ++c) sc[c] = fmaf(aj, wv[c], sc[c]);
        }
#pragma unroll
        for (int c = 0; c < 64; ++c) t2[hi * 128 + c0 + c] = sc[c];
    }
    __syncthreads();
    const int c = t & 127, half = t >> 7;
    float acc[128];
#pragma unroll
    for (int o = 0; o < 128; ++o) acc[o] = 0.f;
    for (int ci = half * 64; ci < half * 64 + 64; ++ci) {
        float s = t2[ci * 128 + c];
        const float* pt = PT + ci * 128;
#pragma unroll
        for (int o = 0; o < 128; ++o) acc[o] = fmaf(pt[o], s, acc[o]);
    }
    __syncthreads();
    if (half) {
#pragma unroll
        for (int o = 0; o < 128; ++o) t2[c * 128 + o] = acc[o];
    }
    __syncthreads();
    if (!half) {
        ushort* m = Mbb + (size_t)b * 16384;
#pragma unroll
        for (int o = 0; o < 128; ++o)
            m[(size_t)o * 128 + c] = f2b(acc[o] + t2[c * 128 + o]);
    }
}

// ---------- attnproj: x1pre = Mb x + proj_b + x, LN1 stats. 128-col tile ----------
__global__ __launch_bounds__(256, 3) void k_attnproj(const float* __restrict__ x,
                                                     const ushort* __restrict__ Mbb,
                                                     const float* __restrict__ proj_b,
                                                     float* __restrict__ xout,
                                                     float* __restrict__ st) {
    __shared__ ushort xT[128 * 136];   // [n][c] bf16
    const int b = blockIdx.y;
    const int n0 = blockIdx.x * 128;
    const int t = threadIdx.x;
    {
        const int nn = t & 127, cg = t >> 7;
        const float* xp = x + (size_t)b * DS + n0 + nn;
#pragma unroll
        for (int g = 0; g < 16; ++g) {
            int c0 = cg * 64 + g * 4;
            ushort4 pk;
            pk.x = f2b(xp[(size_t)(c0 + 0) * N_SP]);
            pk.y = f2b(xp[(size_t)(c0 + 1) * N_SP]);
            pk.z = f2b(xp[(size_t)(c0 + 2) * N_SP]);
            pk.w = f2b(xp[(size_t)(c0 + 3) * N_SP]);
            *(ushort4*)&xT[nn * 136 + c0] = pk;
        }
    }
    __syncthreads();
    const int wave = t >> 6, lane = t & 63, q = lane >> 4, r = lane & 15;
    const ushort* mb = Mbb + (size_t)b * 16384;
    f4 acc[8][2];
#pragma unroll
    for (int m = 0; m < 8; ++m) { acc[m][0] = (f4){0,0,0,0}; acc[m][1] = (f4){0,0,0,0}; }
    const int nr0 = wave * 32 + r, nr1 = nr0 + 16;
#pragma unroll
    for (int kk = 0; kk < 4; ++kk) {
        const int c0 = kk * 32 + q * 8;
        s8b b0 = *(const s8b*)&xT[nr0 * 136 + c0];
        s8b b1 = *(const s8b*)&xT[nr1 * 136 + c0];
#pragma unroll
        for (int m = 0; m < 8; ++m) {
            s8b a = *(const s8b*)(mb + (size_t)(m * 16 + r) * 128 + c0);
            acc[m][0] = __builtin_amdgcn_mfma_f32_16x16x32_bf16(a, b0, acc[m][0], 0, 0, 0);
            acc[m][1] = __builtin_amdgcn_mfma_f32_16x16x32_bf16(a, b1, acc[m][1], 0, 0, 0);
        }
    }
    float s = 0.f, sq = 0.f;
#pragma unroll
    for (int n2 = 0; n2 < 2; ++n2) {
        const int nrl = wave * 32 + n2 * 16 + r;
        float* op = xout + (size_t)b * DS + n0 + nrl;
#pragma unroll
        for (int m = 0; m < 8; ++m) {
            const int o0 = m * 16 + q * 4;
            ushort4 xr = *(const ushort4*)&xT[nrl * 136 + o0];
            float v0 = acc[m][n2][0] + proj_b[o0 + 0] + b2f(xr.x);
            float v1 = acc[m][n2][1] + proj_b[o0 + 1] + b2f(xr.y);
            float v2 = acc[m][n2][2] + proj_b[o0 + 2] + b2f(xr.z);
            float v3 = acc[m][n2][3] + proj_b[o0 + 3] + b2f(xr.w);
            op[(size_t)(o0 + 0) * N_SP] = v0;
            op[(size_t)(o0 + 1) * N_SP] = v1;
            op[(size_t)(o0 + 2) * N_SP] = v2;
            op[(size_t)(o0 + 3) * N_SP] = v3;
            s += (v0 + v1) + (v2 + v3);
            sq = fmaf(v0, v0, sq); sq = fmaf(v1, v1, sq);
            sq = fmaf(v2, v2, sq); sq = fmaf(v3, v3, sq);
        }
    }
#pragma unroll
    for (int off = 32; off > 0; off >>= 1) {
        s += __shfl_down(s, off, 64);
        sq += __shfl_down(sq, off, 64);
    }
    if (lane == 0) {
        atomicAdd(&st[0 + b], s);
        atomicAdd(&st[8 + b], sq);
    }
}

__global__ void k_finalize(float* st, int off) {
    int b = threadIdx.x;
    if (b < 8) {
        const float invn = 1.0f / 4194304.0f;
        float mu = st[off + b] * invn;
        float var = st[off + 8 + b] * invn - mu * mu;
        st[off + 16 + b] = mu;
        st[off + 24 + b] = rsqrtf(var + 1e-5f);
    }
}

__global__ __launch_bounds__(256) void k_lnapply(const float* __restrict__ in,
                                                 const float* __restrict__ lnw,
                                                 const float* __restrict__ lnb,
                                                 const float* __restrict__ st, int off,
                                                 float* __restrict__ out) {
    size_t i4 = (size_t)blockIdx.x * 256 + threadIdx.x;
    int b = (int)(i4 >> 20);
    size_t cn = i4 * 4 - (size_t)b * 4194304;
    float mu = st[off + 16 + b], rs = st[off + 24 + b];
    const float4 xv = *(const float4*)(in + (size_t)b * DS + cn);
    const float4 wv = *(const float4*)(lnw + cn);
    const float4 bv = *(const float4*)(lnb + cn);
    float4 o;
    o.x = (xv.x - mu) * rs * wv.x + bv.x;
    o.y = (xv.y - mu) * rs * wv.y + bv.y;
    o.z = (xv.z - mu) * rs * wv.z + bv.z;
    o.w = (xv.w - mu) * rs * wv.w + bv.w;
    *(float4*)(out + (size_t)b * DS + cn) = o;
}

// ---------- fused LN1-apply + MLP + residual + LN2 stats, 128-col tile ----------
__global__ __launch_bounds__(256, 2) void k_mlp(float* __restrict__ xio,
                                                const ushort* __restrict__ w1b,
                                                const float* __restrict__ b1v,
                                                const ushort* __restrict__ w2b,
                                                const float* __restrict__ b2v,
                                                const float* __restrict__ lnw,
                                                const float* __restrict__ lnb,
                                                float* __restrict__ st) {
    __shared__ ushort xT[128 * 128];   // swizzled, x1 = LN1(x1pre) bf16
    __shared__ ushort hT[128 * 128];   // swizzled, gelu slice bf16
    const int b = blockIdx.y;
    const int n0 = blockIdx.x * 128;
    const int t = threadIdx.x;
    const float mu = st[16 + b], rs = st[24 + b];
    {
        const int nn = t & 127, cg = t >> 7;
        const float* xp = xio + (size_t)b * DS + n0 + nn;
        const float* wp = lnw + n0 + nn;
        const float* bp = lnb + n0 + nn;
#pragma unroll
        for (int g = 0; g < 16; ++g) {
            int c0 = cg * 64 + g * 4;
            ushort4 pk;
            pk.x = f2b(fmaf((xp[(size_t)(c0 + 0) * N_SP] - mu) * rs,
                            wp[(size_t)(c0 + 0) * N_SP], bp[(size_t)(c0 + 0) * N_SP]));
            pk.y = f2b(fmaf((xp[(size_t)(c0 + 1) * N_SP] - mu) * rs,
                            wp[(size_t)(c0 + 1) * N_SP], bp[(size_t)(c0 + 1) * N_SP]));
            pk.z = f2b(fmaf((xp[(size_t)(c0 + 2) * N_SP] - mu) * rs,
                            wp[(size_t)(c0 + 2) * N_SP], bp[(size_t)(c0 + 2) * N_SP]));
            pk.w = f2b(fmaf((xp[(size_t)(c0 + 3) * N_SP] - mu) * rs,
                            wp[(size_t)(c0 + 3) * N_SP], bp[(size_t)(c0 + 3) * N_SP]));
            *(ushort4*)&xT[swz4(nn, c0)] = pk;
        }
    }
    __syncthreads();
    const int wave = t >> 6, lane = t & 63, q = lane >> 4, r = lane & 15;
    const int nr0 = wave * 32 + r, nr1 = nr0 + 16;
    f4 acc2[8][2];
#pragma unroll
    for (int m = 0; m < 8; ++m) { acc2[m][0] = (f4){0,0,0,0}; acc2[m][1] = (f4){0,0,0,0}; }

    for (int os = 0; os < 4; ++os) {
        f4 acc1[8][2];
#pragma unroll
        for (int m = 0; m < 8; ++m) { acc1[m][0] = (f4){0,0,0,0}; acc1[m][1] = (f4){0,0,0,0}; }
#pragma unroll
        for (int kk = 0; kk < 4; ++kk) {
            const int c0 = kk * 32 + q * 8;
            s8b b0 = *(const s8b*)&xT[swz8(nr0, c0)];
            s8b b1 = *(const s8b*)&xT[swz8(nr1, c0)];
#pragma unroll
            for (int m = 0; m < 8; ++m) {
                s8b a = *(const s8b*)(w1b + (size_t)(os * 128 + m * 16 + r) * 128 + c0);
                acc1[m][0] = __builtin_amdgcn_mfma_f32_16x16x32_bf16(a, b0, acc1[m][0], 0, 0, 0);
                acc1[m][1] = __builtin_amdgcn_mfma_f32_16x16x32_bf16(a, b1, acc1[m][1], 0, 0, 0);
            }
        }
        __syncthreads();   // prior phase-2 hT reads complete
#pragma unroll
        for (int n2 = 0; n2 < 2; ++n2) {
            const int nr = wave * 32 + n2 * 16 + r;
#pragma unroll
            for (int m = 0; m < 8; ++m) {
                const int o0 = m * 16 + q * 4;
                ushort4 pk;
                pk.x = f2b(gelu_f(acc1[m][n2][0] + b1v[os * 128 + o0 + 0]));
                pk.y = f2b(gelu_f(acc1[m][n2][1] + b1v[os * 128 + o0 + 1]));
                pk.z = f2b(gelu_f(acc1[m][n2][2] + b1v[os * 128 + o0 + 2]));
                pk.w = f2b(gelu_f(acc1[m][n2][3] + b1v[os * 128 + o0 + 3]));
                *(ushort4*)&hT[swz4(nr, o0)] = pk;
            }
        }
        __syncthreads();
#pragma unroll
        for (int kk = 0; kk < 4; ++kk) {
            const int c0 = kk * 32 + q * 8;
            s8b h0 = *(const s8b*)&hT[swz8(nr0, c0)];
            s8b h1 = *(const s8b*)&hT[swz8(nr1, c0)];
#pragma unroll
            for (int m = 0; m < 8; ++m) {
                s8b a = *(const s8b*)(w2b + (size_t)(m * 16 + r) * 512 + os * 128 + c0);
                acc2[m][0] = __builtin_amdgcn_mfma_f32_16x16x32_bf16(a, h0, acc2[m][0], 0, 0, 0);
                acc2[m][1] = __builtin_amdgcn_mfma_f32_16x16x32_bf16(a, h1, acc2[m][1], 0, 0, 0);
            }
        }
    }
    float s = 0.f, sq = 0.f;
#pragma unroll
    for (int n2 = 0; n2 < 2; ++n2) {
        const int nrl = wave * 32 + n2 * 16 + r;
        float* op = xio + (size_t)b * DS + n0 + nrl;
#pragma unroll
        for (int m = 0; m < 8; ++m) {
            const int o0 = m * 16 + q * 4;
            ushort4 xr = *(const ushort4*)&xT[swz4(nrl, o0)];
            float v0 = acc2[m][n2][0] + b2v[o0 + 0] + b2f(xr.x);
            float v1 = acc2[m][n2][1] + b2v[o0 + 1] + b2f(xr.y);
            float v2 = acc2[m][n2][2] + b2v[o0 + 2] + b2f(xr.z);
            float v3 = acc2[m][n2][3] + b2v[o0 + 3] + b2f(xr.w);
            op[(size_t)(o0 + 0) * N_SP] = v0;
            op[(size_t)(o0 + 1) * N_SP] = v1;
            op[(size_t)(o0 + 2) * N_SP] = v2;
            op[(size_t)(o0 + 3) * N_SP] = v3;
            s += (v0 + v1) + (v2 + v3);
            sq = fmaf(v0, v0, sq); sq = fmaf(v1, v1, sq);
            sq = fmaf(v2, v2, sq); sq = fmaf(v3, v3, sq);
        }
    }
#pragma unroll
    for (int off = 32; off > 0; off >>= 1) {
        s += __shfl_down(s, off, 64);
        sq += __shfl_down(sq, off, 64);
    }
    if (lane == 0) {
        atomicAdd(&st[32 + b], s);
        atomicAdd(&st[40 + b], sq);
    }
}

extern "C" void kernel_launch(void* const* d_in, const int* in_sizes, int n_in,
                              void* d_out, int out_size, void* d_ws, size_t ws_size,
                              hipStream_t stream) {
    const float* x      = (const float*)d_in[0];
    const float* qkv_w  = (const float*)d_in[1];
    const float* proj_w = (const float*)d_in[2];
    const float* proj_b = (const float*)d_in[3];
    const float* ln1_w  = (const float*)d_in[4];
    const float* ln1_b  = (const float*)d_in[5];
    const float* ln2_w  = (const float*)d_in[6];
    const float* ln2_b  = (const float*)d_in[7];
    const float* mlp_w1 = (const float*)d_in[8];
    const float* mlp_b1 = (const float*)d_in[9];
    const float* mlp_w2 = (const float*)d_in[10];
    const float* mlp_b2 = (const float*)d_in[11];
    float* out = (float*)d_out;

    char* wsb = (char*)d_ws;
    float*  Gpart = (float*)wsb;                      // 33,554,432 B
    float*  G     = (float*)(wsb + 33554432);         // 524,288
    float*  attn  = (float*)(wsb + 34078720);         // 65,536
    float*  PT    = (float*)(wsb + 34144256);         // 65,536
    float*  st    = (float*)(wsb + 34209792);         // 256
    ushort* Mbb   = (ushort*)(wsb + 34210048);        // 262,144
    ushort* w1b   = (ushort*)(wsb + 34472192);        // 131,072
    ushort* w2b   = (ushort*)(wsb + 34603264);        // 131,072

    hipMemsetAsync(st, 0, 64 * sizeof(float), stream);

    k_transpose<<<64, 256, 0, stream>>>(proj_w, PT, 128, 128);
    k_cvt<<<256, 256, 0, stream>>>(mlp_w1, w1b, 65536);
    k_cvt<<<256, 256, 0, stream>>>(mlp_w2, w2b, 65536);

    k_cov<<<dim3(64, 8), 256, 0, stream>>>(x, Gpart);
    k_greduce<<<512, 256, 0, stream>>>(Gpart, G);
    k_gram_small<<<64, 256, 0, stream>>>(G, qkv_w, attn);
    k_mfold<<<8, 256, 0, stream>>>(attn, qkv_w, PT, Mbb);

    k_attnproj<<<dim3(256, 8), 256, 0, stream>>>(x, Mbb, proj_b, out, st);
    k_finalize<<<1, 64, 0, stream>>>(st, 0);
    // LN1 apply fused into k_mlp staging
    k_mlp<<<dim3(256, 8), 256, 0, stream>>>(out, w1b, mlp_b1, w2b, mlp_b2,
                                            ln1_w, ln1_b, st);
    k_finalize<<<1, 64, 0, stream>>>(st, 32);
    k_lnapply<<<32768, 256, 0, stream>>>(out, ln2_w, ln2_b, st, 32, out);
}